// Round 9
// baseline (429.472 us; speedup 1.0000x reference)
//
#include <hip/hip_runtime.h>
#include <hip/hip_bf16.h>

#define NQ 12
#define NL 5
#define DIM 4096
#define BATCH 4096
#define TILE 128
#define BK 64
#define NIT (DIM / BK)                  // 64
#define NTILE (BATCH / TILE)            // 32
#define NBLK (NTILE * (NTILE + 1) / 2)  // 528
#define NXCD 8
#define CPX (NBLK / NXCD)               // 66, exact -> bijective swizzle

typedef __bf16 bf16x8 __attribute__((ext_vector_type(8)));
typedef float f32x16 __attribute__((ext_vector_type(16)));
typedef unsigned int u32x4 __attribute__((ext_vector_type(4)));
typedef unsigned short u16x8 __attribute__((ext_vector_type(8)));
typedef unsigned int u32;
typedef unsigned short u16;

#define MFMA32(a, b, c) __builtin_amdgcn_mfma_f32_32x32x16_bf16(a, b, c, 0, 0, 0)

// float -> bf16 bits, round-to-nearest-even
__device__ static inline u16 f32_to_bf16_bits(float x) {
    u32 b = __builtin_bit_cast(u32, x);
    b += 0x7fffu + ((b >> 16) & 1u);
    return (u16)(b >> 16);
}

// async 16B global->LDS; HW writes wave-uniform lds base + lane*16.
__device__ static inline void async_copy16(const void* g, void* l) {
    __builtin_amdgcn_global_load_lds((const __attribute__((address_space(1))) u32*)g,
                                     (__attribute__((address_space(3))) u32*)l, 16, 0, 0);
}

// complex helpers
__device__ static inline float2 cmul(float2 m, float2 a) {
    return make_float2(m.x * a.x - m.y * a.y, m.x * a.y + m.y * a.x);
}
__device__ static inline float2 cadd(float2 a, float2 b) {
    return make_float2(a.x + b.x, a.y + b.y);
}

// tile index p (0..527) -> (bi, bj), bi <= bj
__device__ static inline void tile_of(int p, int* bi, int* bj) {
    int rem = p, b = 0;
    while (rem >= NTILE - b) { rem -= NTILE - b; ++b; }
    *bi = b; *bj = b + rem;
}

// ---------------------------------------------------------------------------
// Kernel A: batch-independent part (layers 0..3 full, layer 4 param gates).
// ---------------------------------------------------------------------------
__global__ __launch_bounds__(1024) void qnn_base(const float* __restrict__ params,
                                                 float2* __restrict__ psi1) {
    __shared__ float2 st[DIM];
    __shared__ float2 U[NL * NQ][4];
    const int t = threadIdx.x;

    for (int k = t; k < DIM; k += 1024) st[k] = make_float2(k == 0 ? 1.f : 0.f, 0.f);

    if (t < NL * NQ) {
        float phi = params[t * 3 + 0], th = params[t * 3 + 1], lam = params[t * 3 + 2];
        float c = cosf(0.5f * th), s = sinf(0.5f * th);
        float ap = 0.5f * (lam + phi), am = 0.5f * (lam - phi);
        // M = U^T, U = Rz(lam) Ry(th) Rz(phi)
        U[t][0] = make_float2(c * cosf(ap), -c * sinf(ap));
        U[t][1] = make_float2(s * cosf(am), s * sinf(am));
        U[t][2] = make_float2(-s * cosf(am), s * sinf(am));
        U[t][3] = make_float2(c * cosf(ap), c * sinf(ap));
    }
    __syncthreads();

    for (int l = 0; l < NL; ++l) {
        for (int qq = 0; qq < NQ; qq += 2) {
            const float2* M1 = U[l * NQ + qq];
            const float2* M2 = U[l * NQ + qq + 1];
            const int b2 = 10 - qq;              // bit of qubit qq+1
            const int s2 = 1 << b2, s1 = s2 << 1;
            int hi = t >> b2, lo = t & (s2 - 1);
            int i00 = (hi << (b2 + 2)) | lo;
            int i01 = i00 + s2, i10 = i00 + s1, i11 = i10 + s2;
            float2 a00 = st[i00], a01 = st[i01], a10 = st[i10], a11 = st[i11];
            float2 b00 = cadd(cmul(M1[0], a00), cmul(M1[1], a10));
            float2 b10 = cadd(cmul(M1[2], a00), cmul(M1[3], a10));
            float2 b01 = cadd(cmul(M1[0], a01), cmul(M1[1], a11));
            float2 b11 = cadd(cmul(M1[2], a01), cmul(M1[3], a11));
            st[i00] = cadd(cmul(M2[0], b00), cmul(M2[1], b01));
            st[i01] = cadd(cmul(M2[2], b00), cmul(M2[3], b01));
            st[i10] = cadd(cmul(M2[0], b10), cmul(M2[1], b11));
            st[i11] = cadd(cmul(M2[2], b10), cmul(M2[3], b11));
            __syncthreads();
        }
        if (l < NL - 1) {
            float2 v[4];
            #pragma unroll
            for (int u = 0; u < 4; ++u) {
                int k = t * 4 + u, j = k;
                #pragma unroll
                for (int q = 10; q >= 0; --q) j ^= ((j >> (11 - q)) & 1) << (10 - q);
                v[u] = st[j];
            }
            __syncthreads();
            #pragma unroll
            for (int u = 0; u < 4; ++u) st[t * 4 + u] = v[u];
            __syncthreads();
        }
    }
    for (int k = t; k < DIM; k += 1024) psi1[k] = st[k];
}

// ---------------------------------------------------------------------------
// Kernel M: m_x = psi1^T J_x conj(psi1), x in [0,4096).
// (J_x v)_d = sign(d,x) v_{d^x}, sign = -1 iff popc(x & ~d) odd.
// ---------------------------------------------------------------------------
__global__ __launch_bounds__(256) void qnn_m(const float2* __restrict__ psi1,
                                             float2* __restrict__ m) {
    __shared__ float2 st[DIM];
    __shared__ float2 red[4];
    const int t = threadIdx.x;
    for (int k = t; k < DIM; k += 256) st[k] = psi1[k];
    __syncthreads();
    for (int xi = 0; xi < 16; ++xi) {
        const int x = blockIdx.x * 16 + xi;
        float sre = 0.f, sim = 0.f;
        for (int d = t; d < DIM; d += 256) {
            float2 a = st[d];
            float2 b = st[d ^ x];
            float sgn = (__popc(x & ~d) & 1) ? -1.f : 1.f;
            sre += sgn * (a.x * b.x + a.y * b.y);   // a * conj(b)
            sim += sgn * (a.y * b.x - a.x * b.y);
        }
        #pragma unroll
        for (int o = 32; o; o >>= 1) {
            sre += __shfl_down(sre, o);
            sim += __shfl_down(sim, o);
        }
        if ((t & 63) == 0) red[t >> 6] = make_float2(sre, sim);
        __syncthreads();
        if (t == 0)
            m[x] = make_float2(red[0].x + red[1].x + red[2].x + red[3].x,
                               red[0].y + red[1].y + red[2].y + red[3].y);
        __syncthreads();
    }
}

// ---------------------------------------------------------------------------
// Kernel B': w(b) = (tensor_q B(a_bq)) m with symmetric B = [[c,s],[s,-c]].
// u is NOT materialized anymore (synthesized in-register in the Gram).
// ---------------------------------------------------------------------------
__global__ __launch_bounds__(1024) void qnn_wu(const float* __restrict__ X,
                                               const float2* __restrict__ m,
                                               u16* __restrict__ WR,
                                               u16* __restrict__ WI) {
    __shared__ float2 st[DIM];
    __shared__ float cs[NQ], sn[NQ];
    const int b = blockIdx.x;
    const int t = threadIdx.x;

    for (int k = t; k < DIM; k += 1024) st[k] = m[k];
    if (t < NQ) {
        float a = 0.5f * X[b * NQ + t];
        cs[t] = cosf(a); sn[t] = sinf(a);
    }
    __syncthreads();

    for (int qq = 0; qq < NQ; qq += 2) {
        const float c1 = cs[qq], s1v = sn[qq];
        const float c2 = cs[qq + 1], s2v = sn[qq + 1];
        const int b2 = 10 - qq;
        const int s2 = 1 << b2, s1 = s2 << 1;
        int hi = t >> b2, lo = t & (s2 - 1);
        int i00 = (hi << (b2 + 2)) | lo;
        int i01 = i00 + s2, i10 = i00 + s1, i11 = i10 + s2;
        float2 a00 = st[i00], a01 = st[i01], a10 = st[i10], a11 = st[i11];
        float2 b00 = make_float2(c1 * a00.x + s1v * a10.x, c1 * a00.y + s1v * a10.y);
        float2 b10 = make_float2(s1v * a00.x - c1 * a10.x, s1v * a00.y - c1 * a10.y);
        float2 b01 = make_float2(c1 * a01.x + s1v * a11.x, c1 * a01.y + s1v * a11.y);
        float2 b11 = make_float2(s1v * a01.x - c1 * a11.x, s1v * a01.y - c1 * a11.y);
        st[i00] = make_float2(c2 * b00.x + s2v * b01.x, c2 * b00.y + s2v * b01.y);
        st[i01] = make_float2(s2v * b00.x - c2 * b01.x, s2v * b00.y - c2 * b01.y);
        st[i10] = make_float2(c2 * b10.x + s2v * b11.x, c2 * b10.y + s2v * b11.y);
        st[i11] = make_float2(s2v * b10.x - c2 * b11.x, s2v * b10.y - c2 * b11.y);
        __syncthreads();
    }

    u16 hr[4], hi4[4];
    #pragma unroll
    for (int u = 0; u < 4; ++u) {
        float2 a = st[t * 4 + u];
        hr[u] = f32_to_bf16_bits(a.x);
        hi4[u] = f32_to_bf16_bits(a.y);
    }
    *(ushort4*)&WR[(size_t)b * DIM + t * 4] = make_ushort4(hr[0], hr[1], hr[2], hr[3]);
    *(ushort4*)&WI[(size_t)b * DIM + t * 4] = make_ushort4(hi4[0], hi4[1], hi4[2], hi4[3]);
}

// ---------------------------------------------------------------------------
// Kernel C': G_ij = sum_k u[j][k] w[i][k]; K = Re^2 + Im^2.
// u synthesized IN-REGISTER from its rank-1 tensor structure:
//   u[j][k] = prod_q (bit(k,11-q) ? sin : cos)(X[j][q]/2)
//   k = it*64 + k16*16 + half*8 + d  (it = 6 high bits exactly, NIT=64)
//   u = Uhi[j][it] * Umid[j][k16|half] * Ud[j][d]   (tiny per-lane tables)
// -> staging is W ONLY: 2 planes x [128][128B] = 32 KB/iter (-33% bytes vs
// R8; kernel is delivery-bound at ~26 GB/s/CU so bytes ~= time). LDS 32 KB.
// R0 loop order; XCD bijective swizzle (W panels L2/L3-resident).
// chunk swizzle phys = logchunk ^ ((row>>1)&3) (verified conflict-free).
// ---------------------------------------------------------------------------
__global__ __launch_bounds__(256, 2) void qnn_gram2(const u16* __restrict__ WR,
                                                    const u16* __restrict__ WI,
                                                    const float* __restrict__ X,
                                                    float* __restrict__ K) {
    const int p = (blockIdx.x % NXCD) * CPX + blockIdx.x / NXCD;
    int bi, bj;
    tile_of(p, &bi, &bj);

    __shared__ __align__(16) unsigned char lds[4][TILE][64];   // 32 KB (W only)
    const int t = threadIdx.x;
    const int w = t >> 6, lane = t & 63;
    const int half = lane >> 5, l31 = lane & 31;
    const int wm = (w >> 1) * 64, wn = (w & 1) * 64;
    const int rowA = bi * TILE, rowB = bj * TILE;
    const int srow16 = lane >> 2;   // 0..15
    const int sphys = lane & 3;

    f32x16 accRe[2][2], accIm[2][2];
    #pragma unroll
    for (int a = 0; a < 2; ++a)
        #pragma unroll
        for (int b = 0; b < 2; ++b) {
            #pragma unroll
            for (int r = 0; r < 16; ++r) { accRe[a][b][r] = 0.f; accIm[a][b][r] = 0.f; }
        }

    // ---- per-lane u tables (once per block) ----
    // j columns owned by this lane: j = rowB + wn + ni*32 + l31, ni in {0,1}
    float csh[2][6], snh[2][6], Umid[2][4], Ud[2][8];
    #pragma unroll
    for (int ni = 0; ni < 2; ++ni) {
        const int j = rowB + wn + ni * 32 + l31;
        float c[NQ], s[NQ];
        #pragma unroll
        for (int q = 0; q < NQ; ++q) {
            float a = 0.5f * X[j * NQ + q];
            c[q] = cosf(a); s[q] = sinf(a);
        }
        #pragma unroll
        for (int q = 0; q < 6; ++q) { csh[ni][q] = c[q]; snh[ni][q] = s[q]; }
        #pragma unroll
        for (int k16 = 0; k16 < 4; ++k16) {
            float f6 = (k16 & 2) ? s[6] : c[6];
            float f7 = (k16 & 1) ? s[7] : c[7];
            float f8 = half ? s[8] : c[8];
            Umid[ni][k16] = f6 * f7 * f8;
        }
        #pragma unroll
        for (int d = 0; d < 8; ++d)
            Ud[ni][d] = ((d & 4) ? s[9] : c[9]) * ((d & 2) ? s[10] : c[10])
                      * ((d & 1) ? s[11] : c[11]);
    }

    // staging: W only. per plane pl in {WR, WI}: sub-planes (pl*2+kh);
    // slot s = w*2+jj; lane -> row = s*16 + (lane>>2), phys chunk = lane&3,
    // global logchunk = (lane&3) ^ ((row>>1)&3). 8 instr/thread per ISSUE.
#define ISSUE2(it)                                                                      \
    do {                                                                                \
        const size_t kbase = (size_t)(it) * (BK * 2);                                   \
        _Pragma("unroll")                                                               \
        for (int pl = 0; pl < 2; ++pl) {                                                \
            const u16* src = pl ? WI : WR;                                              \
            _Pragma("unroll")                                                           \
            for (int kh = 0; kh < 2; ++kh) {                                            \
                _Pragma("unroll")                                                       \
                for (int jj = 0; jj < 2; ++jj) {                                        \
                    int s = w * 2 + jj;                                                 \
                    int row = s * 16 + srow16;                                          \
                    int logc = sphys ^ ((row >> 1) & 3);                                \
                    const char* gp = (const char*)src                                   \
                        + (size_t)(rowA + row) * (DIM * 2) + kbase + kh * 64            \
                        + logc * 16;                                                    \
                    char* lp = (char*)lds + (pl * 2 + kh) * 8192 + s * 1024;            \
                    async_copy16(gp, lp);                                               \
                }                                                                       \
            }                                                                           \
        }                                                                               \
    } while (0)

    ISSUE2(0);
    for (int it = 0; it < NIT; ++it) {
        __syncthreads();   // drains vmcnt: buffer holds iter 'it'

        // A-frags from LDS: W rows r = wm + mi*32 + l31, k-chunk (k16, half)
        bf16x8 fWR[2][4], fWI[2][4];
        #pragma unroll
        for (int mi = 0; mi < 2; ++mi) {
            int r = wm + mi * 32 + l31;
            int sw = (r >> 1) & 3;
            #pragma unroll
            for (int k16 = 0; k16 < 4; ++k16) {
                int kh = k16 >> 1;
                int phys = (((k16 & 1) * 2 + half) ^ sw);
                fWR[mi][k16] = *(const bf16x8*)((const char*)lds + (0 + kh) * 8192 + r * 64 + phys * 16);
                fWI[mi][k16] = *(const bf16x8*)((const char*)lds + (2 + kh) * 8192 + r * 64 + phys * 16);
            }
        }

        __syncthreads();   // all waves done reading LDS
        if (it + 1 < NIT) ISSUE2(it + 1);   // overlaps u-build + MFMA below

        // ---- synthesize B-frags (u) in registers ----
        float Uhi[2];
        #pragma unroll
        for (int ni = 0; ni < 2; ++ni) {
            float v = ((it >> 5) & 1) ? snh[ni][0] : csh[ni][0];
            v *= ((it >> 4) & 1) ? snh[ni][1] : csh[ni][1];
            v *= ((it >> 3) & 1) ? snh[ni][2] : csh[ni][2];
            v *= ((it >> 2) & 1) ? snh[ni][3] : csh[ni][3];
            v *= ((it >> 1) & 1) ? snh[ni][4] : csh[ni][4];
            v *= (it & 1) ? snh[ni][5] : csh[ni][5];
            Uhi[ni] = v;
        }
        bf16x8 fU[2][4];
        #pragma unroll
        for (int ni = 0; ni < 2; ++ni)
            #pragma unroll
            for (int k16 = 0; k16 < 4; ++k16) {
                float sc = Uhi[ni] * Umid[ni][k16];
                u16x8 h;
                #pragma unroll
                for (int d = 0; d < 8; ++d)
                    h[d] = f32_to_bf16_bits(sc * Ud[ni][d]);
                fU[ni][k16] = __builtin_bit_cast(bf16x8, h);
            }

        // grouped by term: same-accumulator reuse distance = 4 MFMAs
        #pragma unroll
        for (int k16 = 0; k16 < 4; ++k16) {
            #pragma unroll
            for (int mi = 0; mi < 2; ++mi)
                #pragma unroll
                for (int ni = 0; ni < 2; ++ni)
                    accRe[mi][ni] = MFMA32(fWR[mi][k16], fU[ni][k16], accRe[mi][ni]);
            #pragma unroll
            for (int mi = 0; mi < 2; ++mi)
                #pragma unroll
                for (int ni = 0; ni < 2; ++ni)
                    accIm[mi][ni] = MFMA32(fWI[mi][k16], fU[ni][k16], accIm[mi][ni]);
        }
    }
#undef ISSUE2

    // epilogue: C/D 32x32 layout col=lane&31, row=(reg&3)+8*(reg>>2)+4*(lane>>5)
    const int iBase = rowA + wm;
    const int jBase = rowB + wn;
    #pragma unroll
    for (int mi = 0; mi < 2; ++mi)
        #pragma unroll
        for (int ni = 0; ni < 2; ++ni)
            #pragma unroll
            for (int r = 0; r < 16; ++r) {
                int row32 = (r & 3) + 8 * (r >> 2) + 4 * half;
                int i = iBase + mi * 32 + row32;
                int j = jBase + ni * 32 + l31;
                float re = accRe[mi][ni][r];
                float im = accIm[mi][ni][r];
                float v = re * re + im * im;
                if (i == j) v = 1.0f;
                K[(size_t)i * BATCH + j] = v;
                if (bi != bj) K[(size_t)j * BATCH + i] = v;
            }
}

extern "C" void kernel_launch(void* const* d_in, const int* in_sizes, int n_in,
                              void* d_out, int out_size, void* d_ws, size_t ws_size,
                              hipStream_t stream) {
    const float* X = (const float*)d_in[0];
    const float* params = (const float*)d_in[1];
    float* K = (float*)d_out;

    const size_t plane = (size_t)BATCH * DIM * sizeof(u16);   // 32 MB
    // layout: psi1 @0 (32KB) | m @65536 (32KB) | WR @131072 | WI
    float2* psi1 = (float2*)d_ws;
    float2* m = (float2*)((char*)d_ws + 65536);
    u16* WR = (u16*)((char*)d_ws + 131072);
    u16* WI = (u16*)((char*)WR + plane);

    hipLaunchKernelGGL(qnn_base, dim3(1), dim3(1024), 0, stream, params, psi1);
    hipLaunchKernelGGL(qnn_m, dim3(256), dim3(256), 0, stream, psi1, m);
    hipLaunchKernelGGL(qnn_wu, dim3(BATCH), dim3(1024), 0, stream, X, m, WR, WI);
    hipLaunchKernelGGL(qnn_gram2, dim3(NBLK), dim3(256), 0, stream, WR, WI, X, K);
}

// Round 10
// 390.830 us; speedup vs baseline: 1.0989x; 1.0989x over previous
//
#include <hip/hip_runtime.h>
#include <hip/hip_bf16.h>

#define NQ 12
#define NL 5
#define DIM 4096
#define BATCH 4096
#define BK 64
#define NIT (DIM / BK)                  // 64
// gram tile: 64 rows (W, staged) x 256 cols (u, synthesized)
#define TROW 64
#define TCOL 256
#define NRT (BATCH / TROW)              // 64
#define NCT (BATCH / TCOL)              // 16
#define NBLK3 544                       // sum_{ct=0..15} (4ct+4)
#define NXCD 8
#define CPX3 (NBLK3 / NXCD)             // 68, exact -> bijective swizzle

typedef __bf16 bf16x8 __attribute__((ext_vector_type(8)));
typedef float f32x16 __attribute__((ext_vector_type(16)));
typedef unsigned int u32x4 __attribute__((ext_vector_type(4)));
typedef unsigned int u32;
typedef unsigned short u16;

#define MFMA32(a, b, c) __builtin_amdgcn_mfma_f32_32x32x16_bf16(a, b, c, 0, 0, 0)

// float -> bf16 bits, round-to-nearest-even
__device__ static inline u16 f32_to_bf16_bits(float x) {
    u32 b = __builtin_bit_cast(u32, x);
    b += 0x7fffu + ((b >> 16) & 1u);
    return (u16)(b >> 16);
}

// packed f32x2 -> bf16x2 HW convert (1 instr for 2 values)
__device__ static inline u32 cvt_pk_bf16(float lo, float hi) {
    u32 r;
    asm volatile("v_cvt_pk_bf16_f32 %0, %1, %2" : "=v"(r) : "v"(lo), "v"(hi));
    return r;
}

// async 16B global->LDS; HW writes wave-uniform lds base + lane*16.
__device__ static inline void async_copy16(const void* g, void* l) {
    __builtin_amdgcn_global_load_lds((const __attribute__((address_space(1))) u32*)g,
                                     (__attribute__((address_space(3))) u32*)l, 16, 0, 0);
}

// complex helpers
__device__ static inline float2 cmul(float2 m, float2 a) {
    return make_float2(m.x * a.x - m.y * a.y, m.x * a.y + m.y * a.x);
}
__device__ static inline float2 cadd(float2 a, float2 b) {
    return make_float2(a.x + b.x, a.y + b.y);
}

// gram3 tile index p (0..543) -> (rt, ct): for ct, rt in 0..4ct+3
__device__ static inline void tile3_of(int p, int* rt, int* ct) {
    int c = 0, rem = p;
    while (rem >= 4 * c + 4) { rem -= 4 * c + 4; ++c; }
    *ct = c; *rt = rem;
}

// ---------------------------------------------------------------------------
// Kernel A: batch-independent part (layers 0..3 full, layer 4 param gates).
// ---------------------------------------------------------------------------
__global__ __launch_bounds__(1024) void qnn_base(const float* __restrict__ params,
                                                 float2* __restrict__ psi1) {
    __shared__ float2 st[DIM];
    __shared__ float2 U[NL * NQ][4];
    const int t = threadIdx.x;

    for (int k = t; k < DIM; k += 1024) st[k] = make_float2(k == 0 ? 1.f : 0.f, 0.f);

    if (t < NL * NQ) {
        float phi = params[t * 3 + 0], th = params[t * 3 + 1], lam = params[t * 3 + 2];
        float c = cosf(0.5f * th), s = sinf(0.5f * th);
        float ap = 0.5f * (lam + phi), am = 0.5f * (lam - phi);
        // M = U^T, U = Rz(lam) Ry(th) Rz(phi)
        U[t][0] = make_float2(c * cosf(ap), -c * sinf(ap));
        U[t][1] = make_float2(s * cosf(am), s * sinf(am));
        U[t][2] = make_float2(-s * cosf(am), s * sinf(am));
        U[t][3] = make_float2(c * cosf(ap), c * sinf(ap));
    }
    __syncthreads();

    for (int l = 0; l < NL; ++l) {
        for (int qq = 0; qq < NQ; qq += 2) {
            const float2* M1 = U[l * NQ + qq];
            const float2* M2 = U[l * NQ + qq + 1];
            const int b2 = 10 - qq;              // bit of qubit qq+1
            const int s2 = 1 << b2, s1 = s2 << 1;
            int hi = t >> b2, lo = t & (s2 - 1);
            int i00 = (hi << (b2 + 2)) | lo;
            int i01 = i00 + s2, i10 = i00 + s1, i11 = i10 + s2;
            float2 a00 = st[i00], a01 = st[i01], a10 = st[i10], a11 = st[i11];
            float2 b00 = cadd(cmul(M1[0], a00), cmul(M1[1], a10));
            float2 b10 = cadd(cmul(M1[2], a00), cmul(M1[3], a10));
            float2 b01 = cadd(cmul(M1[0], a01), cmul(M1[1], a11));
            float2 b11 = cadd(cmul(M1[2], a01), cmul(M1[3], a11));
            st[i00] = cadd(cmul(M2[0], b00), cmul(M2[1], b01));
            st[i01] = cadd(cmul(M2[2], b00), cmul(M2[3], b01));
            st[i10] = cadd(cmul(M2[0], b10), cmul(M2[1], b11));
            st[i11] = cadd(cmul(M2[2], b10), cmul(M2[3], b11));
            __syncthreads();
        }
        if (l < NL - 1) {
            float2 v[4];
            #pragma unroll
            for (int u = 0; u < 4; ++u) {
                int k = t * 4 + u, j = k;
                #pragma unroll
                for (int q = 10; q >= 0; --q) j ^= ((j >> (11 - q)) & 1) << (10 - q);
                v[u] = st[j];
            }
            __syncthreads();
            #pragma unroll
            for (int u = 0; u < 4; ++u) st[t * 4 + u] = v[u];
            __syncthreads();
        }
    }
    for (int k = t; k < DIM; k += 1024) psi1[k] = st[k];
}

// ---------------------------------------------------------------------------
// Kernel M: m_x = psi1^T J_x conj(psi1), x in [0,4096).
// (J_x v)_d = sign(d,x) v_{d^x}, sign = -1 iff popc(x & ~d) odd.
// ---------------------------------------------------------------------------
__global__ __launch_bounds__(256) void qnn_m(const float2* __restrict__ psi1,
                                             float2* __restrict__ m) {
    __shared__ float2 st[DIM];
    __shared__ float2 red[4];
    const int t = threadIdx.x;
    for (int k = t; k < DIM; k += 256) st[k] = psi1[k];
    __syncthreads();
    for (int xi = 0; xi < 16; ++xi) {
        const int x = blockIdx.x * 16 + xi;
        float sre = 0.f, sim = 0.f;
        for (int d = t; d < DIM; d += 256) {
            float2 a = st[d];
            float2 b = st[d ^ x];
            float sgn = (__popc(x & ~d) & 1) ? -1.f : 1.f;
            sre += sgn * (a.x * b.x + a.y * b.y);   // a * conj(b)
            sim += sgn * (a.y * b.x - a.x * b.y);
        }
        #pragma unroll
        for (int o = 32; o; o >>= 1) {
            sre += __shfl_down(sre, o);
            sim += __shfl_down(sim, o);
        }
        if ((t & 63) == 0) red[t >> 6] = make_float2(sre, sim);
        __syncthreads();
        if (t == 0)
            m[x] = make_float2(red[0].x + red[1].x + red[2].x + red[3].x,
                               red[0].y + red[1].y + red[2].y + red[3].y);
        __syncthreads();
    }
}

// ---------------------------------------------------------------------------
// Kernel B': w(b) = (tensor_q B(a_bq)) m with symmetric B = [[c,s],[s,-c]].
// u is synthesized in-register in the Gram (never materialized).
// ---------------------------------------------------------------------------
__global__ __launch_bounds__(1024) void qnn_wu(const float* __restrict__ X,
                                               const float2* __restrict__ m,
                                               u16* __restrict__ WR,
                                               u16* __restrict__ WI) {
    __shared__ float2 st[DIM];
    __shared__ float cs[NQ], sn[NQ];
    const int b = blockIdx.x;
    const int t = threadIdx.x;

    for (int k = t; k < DIM; k += 1024) st[k] = m[k];
    if (t < NQ) {
        float a = 0.5f * X[b * NQ + t];
        cs[t] = cosf(a); sn[t] = sinf(a);
    }
    __syncthreads();

    for (int qq = 0; qq < NQ; qq += 2) {
        const float c1 = cs[qq], s1v = sn[qq];
        const float c2 = cs[qq + 1], s2v = sn[qq + 1];
        const int b2 = 10 - qq;
        const int s2 = 1 << b2, s1 = s2 << 1;
        int hi = t >> b2, lo = t & (s2 - 1);
        int i00 = (hi << (b2 + 2)) | lo;
        int i01 = i00 + s2, i10 = i00 + s1, i11 = i10 + s2;
        float2 a00 = st[i00], a01 = st[i01], a10 = st[i10], a11 = st[i11];
        float2 b00 = make_float2(c1 * a00.x + s1v * a10.x, c1 * a00.y + s1v * a10.y);
        float2 b10 = make_float2(s1v * a00.x - c1 * a10.x, s1v * a00.y - c1 * a10.y);
        float2 b01 = make_float2(c1 * a01.x + s1v * a11.x, c1 * a01.y + s1v * a11.y);
        float2 b11 = make_float2(s1v * a01.x - c1 * a11.x, s1v * a01.y - c1 * a11.y);
        st[i00] = make_float2(c2 * b00.x + s2v * b01.x, c2 * b00.y + s2v * b01.y);
        st[i01] = make_float2(s2v * b00.x - c2 * b01.x, s2v * b00.y - c2 * b01.y);
        st[i10] = make_float2(c2 * b10.x + s2v * b11.x, c2 * b10.y + s2v * b11.y);
        st[i11] = make_float2(s2v * b10.x - c2 * b11.x, s2v * b10.y - c2 * b11.y);
        __syncthreads();
    }

    u16 hr[4], hi4[4];
    #pragma unroll
    for (int u = 0; u < 4; ++u) {
        float2 a = st[t * 4 + u];
        hr[u] = f32_to_bf16_bits(a.x);
        hi4[u] = f32_to_bf16_bits(a.y);
    }
    *(ushort4*)&WR[(size_t)b * DIM + t * 4] = make_ushort4(hr[0], hr[1], hr[2], hr[3]);
    *(ushort4*)&WI[(size_t)b * DIM + t * 4] = make_ushort4(hi4[0], hi4[1], hi4[2], hi4[3]);
}

// ---------------------------------------------------------------------------
// Kernel C'': 64x256 tiles. G_ij = sum_k u[j][k] w[i][k]; K = Re^2+Im^2.
// - W (rows, 64): staged via global_load_lds, 16 KB/iter (bytes/output
//   halved vs 128x128: staged bytes scale with rows, outputs with rows*cols,
//   and cols are FREE because u is synthesized).
// - u (cols, 256): rank-1 synthesis, cvt_pk_bf16 packed converts
//   (~130 VALU/iter/lane vs R9's ~550 — the R9 regression cause).
// - Triangle cover rt <= 4ct+3: 544 blocks = 8 x 68 (bijective XCD swizzle).
//   Near-diagonal tiles double-write a few mirrored cells with
//   transposed-rounding values (Hermitian G -> equal within bf16 tol).
// - 4 waves, wave grid 1x4 (all waves share W rows; per wave 64x64, acc=128).
// LDS: 4 sub-planes [pl*2+kh][64 rows][64 B] = 16 KB;
// chunk swizzle phys = logchunk ^ ((row>>1)&3) (verified conflict-free).
// ---------------------------------------------------------------------------
__global__ __launch_bounds__(256, 2) void qnn_gram3(const u16* __restrict__ WR,
                                                    const u16* __restrict__ WI,
                                                    const float* __restrict__ X,
                                                    float* __restrict__ K) {
    const int p = (blockIdx.x % NXCD) * CPX3 + blockIdx.x / NXCD;
    int rt, ct;
    tile3_of(p, &rt, &ct);

    __shared__ __align__(16) unsigned char lds[4][TROW][64];   // 16 KB
    const int t = threadIdx.x;
    const int w = t >> 6, lane = t & 63;
    const int half = lane >> 5, l31 = lane & 31;
    const int wn = w * 64;                 // column offset of this wave
    const int rowA = rt * TROW, colB = ct * TCOL;
    const int srow16 = lane >> 2;          // 0..15
    const int sphys = lane & 3;

    f32x16 accRe[2][2], accIm[2][2];
    #pragma unroll
    for (int a = 0; a < 2; ++a)
        #pragma unroll
        for (int b = 0; b < 2; ++b) {
            #pragma unroll
            for (int r = 0; r < 16; ++r) { accRe[a][b][r] = 0.f; accIm[a][b][r] = 0.f; }
        }

    // ---- per-lane u tables (once per block) ----
    // j columns owned by this lane: j = colB + wn + ni*32 + l31
    float csh[2][6], snh[2][6], Umid[2][4], Ud[2][8];
    #pragma unroll
    for (int ni = 0; ni < 2; ++ni) {
        const int j = colB + wn + ni * 32 + l31;
        float c[NQ], s[NQ];
        #pragma unroll
        for (int q = 0; q < NQ; ++q) {
            float a = 0.5f * X[j * NQ + q];
            c[q] = cosf(a); s[q] = sinf(a);
        }
        #pragma unroll
        for (int q = 0; q < 6; ++q) { csh[ni][q] = c[q]; snh[ni][q] = s[q]; }
        #pragma unroll
        for (int k16 = 0; k16 < 4; ++k16) {
            float f6 = (k16 & 2) ? s[6] : c[6];
            float f7 = (k16 & 1) ? s[7] : c[7];
            float f8 = half ? s[8] : c[8];
            Umid[ni][k16] = f6 * f7 * f8;
        }
        #pragma unroll
        for (int d = 0; d < 8; ++d)
            Ud[ni][d] = ((d & 4) ? s[9] : c[9]) * ((d & 2) ? s[10] : c[10])
                      * ((d & 1) ? s[11] : c[11]);
    }

    // staging: per (pl,kh) sub-plane: wave w stages rows w*16..w*16+15;
    // lane -> row = w*16 + (lane>>2), phys chunk = lane&3 (HW dest lane*16),
    // global logchunk = (lane&3) ^ ((row>>1)&3). 4 copies/lane per ISSUE.
#define ISSUE3(it)                                                                      \
    do {                                                                                \
        const size_t kbase = (size_t)(it) * (BK * 2);                                   \
        _Pragma("unroll")                                                               \
        for (int pl = 0; pl < 2; ++pl) {                                                \
            const u16* src = pl ? WI : WR;                                              \
            _Pragma("unroll")                                                           \
            for (int kh = 0; kh < 2; ++kh) {                                            \
                int row = w * 16 + srow16;                                              \
                int logc = sphys ^ ((row >> 1) & 3);                                    \
                const char* gp = (const char*)src                                       \
                    + (size_t)(rowA + row) * (DIM * 2) + kbase + kh * 64                \
                    + logc * 16;                                                        \
                char* lp = (char*)lds + (pl * 2 + kh) * 4096 + w * 1024;                \
                async_copy16(gp, lp);                                                   \
            }                                                                           \
        }                                                                               \
    } while (0)

    ISSUE3(0);
    for (int it = 0; it < NIT; ++it) {
        __syncthreads();   // drains vmcnt: buffer holds iter 'it'

        // W frags: rows r = mi*32 + l31 (all waves share), chunk (k16, half)
        bf16x8 fWR[2][4], fWI[2][4];
        #pragma unroll
        for (int mi = 0; mi < 2; ++mi) {
            int r = mi * 32 + l31;
            int sw = (r >> 1) & 3;
            #pragma unroll
            for (int k16 = 0; k16 < 4; ++k16) {
                int kh = k16 >> 1;
                int phys = (((k16 & 1) * 2 + half) ^ sw);
                fWR[mi][k16] = *(const bf16x8*)((const char*)lds + (0 + kh) * 4096 + r * 64 + phys * 16);
                fWI[mi][k16] = *(const bf16x8*)((const char*)lds + (2 + kh) * 4096 + r * 64 + phys * 16);
            }
        }

        __syncthreads();   // all waves done reading LDS
        if (it + 1 < NIT) ISSUE3(it + 1);   // overlaps u-build + MFMA below

        // ---- u high-bit scalar for this iter (6 qubits = 6 bits of it) ----
        float Uhi[2];
        #pragma unroll
        for (int ni = 0; ni < 2; ++ni) {
            float v = ((it >> 5) & 1) ? snh[ni][0] : csh[ni][0];
            v *= ((it >> 4) & 1) ? snh[ni][1] : csh[ni][1];
            v *= ((it >> 3) & 1) ? snh[ni][2] : csh[ni][2];
            v *= ((it >> 2) & 1) ? snh[ni][3] : csh[ni][3];
            v *= ((it >> 1) & 1) ? snh[ni][4] : csh[ni][4];
            v *= (it & 1) ? snh[ni][5] : csh[ni][5];
            Uhi[ni] = v;
        }

        // per k16: synthesize fU (packed converts) then 8 MFMA
        #pragma unroll
        for (int k16 = 0; k16 < 4; ++k16) {
            bf16x8 fU[2];
            #pragma unroll
            for (int ni = 0; ni < 2; ++ni) {
                float sc = Uhi[ni] * Umid[ni][k16];
                u32x4 h;
                h[0] = cvt_pk_bf16(sc * Ud[ni][0], sc * Ud[ni][1]);
                h[1] = cvt_pk_bf16(sc * Ud[ni][2], sc * Ud[ni][3]);
                h[2] = cvt_pk_bf16(sc * Ud[ni][4], sc * Ud[ni][5]);
                h[3] = cvt_pk_bf16(sc * Ud[ni][6], sc * Ud[ni][7]);
                fU[ni] = __builtin_bit_cast(bf16x8, h);
            }
            #pragma unroll
            for (int mi = 0; mi < 2; ++mi)
                #pragma unroll
                for (int ni = 0; ni < 2; ++ni)
                    accRe[mi][ni] = MFMA32(fWR[mi][k16], fU[ni], accRe[mi][ni]);
            #pragma unroll
            for (int mi = 0; mi < 2; ++mi)
                #pragma unroll
                for (int ni = 0; ni < 2; ++ni)
                    accIm[mi][ni] = MFMA32(fWI[mi][k16], fU[ni], accIm[mi][ni]);
        }
    }
#undef ISSUE3

    // epilogue: C/D 32x32 layout col=lane&31, row=(reg&3)+8*(reg>>2)+4*(lane>>5)
    #pragma unroll
    for (int mi = 0; mi < 2; ++mi)
        #pragma unroll
        for (int ni = 0; ni < 2; ++ni)
            #pragma unroll
            for (int r = 0; r < 16; ++r) {
                int row32 = (r & 3) + 8 * (r >> 2) + 4 * half;
                int i = rowA + mi * 32 + row32;
                int j = colB + wn + ni * 32 + l31;
                float re = accRe[mi][ni][r];
                float im = accIm[mi][ni][r];
                float v = re * re + im * im;
                if (i == j) v = 1.0f;
                K[(size_t)i * BATCH + j] = v;
                if (i != j) K[(size_t)j * BATCH + i] = v;
            }
}

extern "C" void kernel_launch(void* const* d_in, const int* in_sizes, int n_in,
                              void* d_out, int out_size, void* d_ws, size_t ws_size,
                              hipStream_t stream) {
    const float* X = (const float*)d_in[0];
    const float* params = (const float*)d_in[1];
    float* K = (float*)d_out;

    const size_t plane = (size_t)BATCH * DIM * sizeof(u16);   // 32 MB
    // layout: psi1 @0 (32KB) | m @65536 (32KB) | WR @131072 | WI
    float2* psi1 = (float2*)d_ws;
    float2* m = (float2*)((char*)d_ws + 65536);
    u16* WR = (u16*)((char*)d_ws + 131072);
    u16* WI = (u16*)((char*)WR + plane);

    hipLaunchKernelGGL(qnn_base, dim3(1), dim3(1024), 0, stream, params, psi1);
    hipLaunchKernelGGL(qnn_m, dim3(256), dim3(256), 0, stream, psi1, m);
    hipLaunchKernelGGL(qnn_wu, dim3(BATCH), dim3(1024), 0, stream, X, m, WR, WI);
    hipLaunchKernelGGL(qnn_gram3, dim3(NBLK3), dim3(256), 0, stream, WR, WI, X, K);
}